// Round 17
// baseline (53.802 us; speedup 1.0000x reference)
//
#include <hip/hip_runtime.h>
#include <math.h>

// Modulated deformable conv v2: B=4, C=256, H=W=64, O=256, K=3, PAD=1
// r34: K3 BARRIER REDUCTION step 2: ring-6 cols (96 KB), barrier per THREE
//      chunks -> 6 barriers (was 9). 3 mega-iters x {3-chunk phase, barrier}
//      x2. Both roles keep TWO named buffers (VGPR budget) with mid-phase
//      reissue; oldest-first vmcnt discipline preserved. Slot parity proof
//      as r33 (slot rewritten 2 barriers after its consumption barrier).
//      K1 = r32 wide-op transpose verbatim; K2 = r27 tile verbatim.

constexpr int Bn = 4;
constexpr int Cn = 256;
constexpr int Hn = 64;
constexpr int Wn = 64;
constexpr int On = 256;
constexpr int PB = Hn * Wn;     // 4096
constexpr int NCH = 27;

typedef __attribute__((ext_vector_type(8))) _Float16 f16x8;  // 4 VGPRs
typedef __attribute__((ext_vector_type(2))) _Float16 f16x2;
typedef __attribute__((ext_vector_type(4))) float f32x4;
typedef __attribute__((ext_vector_type(4))) uint  uint4v;

union FragU { uint4 u; f16x8 h; };

__device__ inline ushort f2h(float f) {
    _Float16 h = (_Float16)f;
    return __builtin_bit_cast(ushort, h);
}
__device__ inline uint pkh(float a, float b) {
    return __builtin_bit_cast(uint, __builtin_amdgcn_cvt_pkrtz(a, b));
}
__device__ inline f16x2 u2h(uint u) { return __builtin_bit_cast(f16x2, u); }
__device__ inline uint h2u(f16x2 h) { return __builtin_bit_cast(uint, h); }

// ---------------------------------------------------------------- kernel 1
// r32: wide-op NCHW fp32 -> NHWC fp16 transpose + weight packs (verbatim).
__global__ __launch_bounds__(256)
void nhwcpack_kernel(const float* __restrict__ x,
                     const float* __restrict__ w,
                     const float* __restrict__ offw,
                     const float* __restrict__ modw,
                     ushort* __restrict__ xhf,
                     ushort* __restrict__ wTb,
                     ushort* __restrict__ owf)
{
    const int bid = blockIdx.x;
    const int b = bid >> 7, seg = bid & 127;
    const int t = threadIdx.x;
    __shared__ float tile2[256][36];   // channel-major; stride 36 -> 16B align

    {
        const int c0 = t >> 3;         // 0..31
        const int q  = t & 7;          // 0..7 -> positions 4q..4q+3
        const float* src = x + (size_t)b * Cn * PB + seg * 32 + 4 * q;
        #pragma unroll
        for (int i = 0; i < 8; ++i) {
            const int c = c0 + i * 32;
            const float4 v = *reinterpret_cast<const float4*>(src + (size_t)c * PB);
            *reinterpret_cast<float4*>(&tile2[c][4 * q]) = v;
        }
    }
    __syncthreads();

    {
        const int c2 = t & 127;        // output word column
        const int ph = t >> 7;         // 0..1
        uint* dH = reinterpret_cast<uint*>(xhf + ((size_t)b * PB + seg * 32) * 256);
        #pragma unroll
        for (int r = 0; r < 2; ++r) {
            const int ppb = (ph + 2 * r) * 8;     // 0,8,16,24
            const float4 a0 = *reinterpret_cast<const float4*>(&tile2[2 * c2][ppb]);
            const float4 a1 = *reinterpret_cast<const float4*>(&tile2[2 * c2][ppb + 4]);
            const float4 b0 = *reinterpret_cast<const float4*>(&tile2[2 * c2 + 1][ppb]);
            const float4 b1 = *reinterpret_cast<const float4*>(&tile2[2 * c2 + 1][ppb + 4]);
            uint wds[8];
            wds[0] = pkh(a0.x, b0.x); wds[1] = pkh(a0.y, b0.y);
            wds[2] = pkh(a0.z, b0.z); wds[3] = pkh(a0.w, b0.w);
            wds[4] = pkh(a1.x, b1.x); wds[5] = pkh(a1.y, b1.y);
            wds[6] = pkh(a1.z, b1.z); wds[7] = pkh(a1.w, b1.w);
            #pragma unroll
            for (int j = 0; j < 8; ++j)
                dH[(size_t)(ppb + j) * 128 + c2] = wds[j];
        }
    }

    #pragma unroll 1
    for (int u = 0; u < 5; ++u) {
        int unit = (u < 4) ? bid * 4 + u : (bid < 256 ? 2048 + bid : -1);
        if (unit < 0) break;
        const int tap = unit >> 8, c = unit & 255;
        const int o = t;
        wTb[((size_t)(unit >> 3) * 256 + o) * 8 + (c & 7)] =
            f2h(w[((size_t)o * Cn + c) * 9 + tap]);
        if (o < 32) {
            float v = 0.f;
            if (o < 18)      v = offw[((size_t)o * Cn + c) * 9 + tap];
            else if (o < 27) v = modw[((size_t)(o - 18) * Cn + c) * 9 + tap];
            owf[((size_t)(unit >> 3) * 32 + o) * 8 + (c & 7)] = f2h(v);
        }
    }
}

// ---------------------------------------------------------------- kernel 2
// r27: offset/mask conv via LDS x-tile direct read (verbatim).
__global__ __launch_bounds__(512, 1)
void offmask_tile_kernel(const ushort* __restrict__ xhf,
                         const float* __restrict__ offb,
                         const float* __restrict__ modb,
                         const ushort* __restrict__ owf,
                         float* __restrict__ offm)
{
    const int hw = blockIdx.x;
    const int blk = (hw & 7) * 32 + (hw >> 3);
    const int b = blk >> 6, row = blk & 63;
    const int t = threadIdx.x;
    const int lane = t & 63;
    const int wv  = t >> 6;
    const int l15 = lane & 15;
    const int g   = lane >> 4;
    const int mt  = wv >> 2;
    const int nt  = wv & 3;

    __shared__ ushort xt[3 * 66 * 256];          // 101,376 B
    uint4* lds4 = reinterpret_cast<uint4*>(xt);  // 16B octets

    {
        const int c  = t >> 3;           // 0..63
        const int og = (t & 7) * 4;      // starting octet 0,4,..,28
        #pragma unroll 1
        for (int r = 0; r < 3; ++r) {
            const int ysrc = row - 1 + r;
            const int ci = c + 1;
            const int base = (r * 66 + ci) * 32;
            if (ysrc >= 0 && ysrc < Hn) {
                const uint4* src = reinterpret_cast<const uint4*>(
                    xhf + ((size_t)(b * PB + ysrc * 64 + c)) * 256);
                #pragma unroll
                for (int j = 0; j < 4; ++j) {
                    const int o = og + j;
                    lds4[base + (o ^ (ci & 7))] = src[o];
                }
            } else {
                const uint4 z = make_uint4(0u, 0u, 0u, 0u);
                #pragma unroll
                for (int j = 0; j < 4; ++j) {
                    const int o = og + j;
                    lds4[base + (o ^ (ci & 7))] = z;
                }
            }
        }
        if (t < 192) {
            const int r = t >> 6, idx = t & 63;
            const int ci = (idx >= 32) ? 65 : 0;
            const int o = idx & 31;
            lds4[(r * 66 + ci) * 32 + (o ^ (ci & 7))] =
                make_uint4(0u, 0u, 0u, 0u);
        }
    }
    __syncthreads();   // the ONLY barrier

    const uint4* owfV = reinterpret_cast<const uint4*>(owf);
    f32x4 acc = (f32x4){0.f, 0.f, 0.f, 0.f};
    const int pos = nt * 16 + l15;

    #pragma unroll 1
    for (int tap = 0; tap < 9; ++tap) {
        const int ty = tap / 3, tx = tap % 3;
        const int ci = pos + tx;
        const int cbase = (ty * 66 + ci) * 32;
        const int cx = ci & 7;

        uint4 aH[8];
        #pragma unroll
        for (int s = 0; s < 8; ++s) {
            const size_t kb = (size_t)((tap * 8 + s) * 4 + g) * 32 + mt * 16 + l15;
            aH[s] = owfV[kb];
        }

        #pragma unroll
        for (int s = 0; s < 8; ++s) {
            FragU aHH, bH;
            aHH.u = aH[s];
            bH.u = lds4[cbase + ((4 * s + g) ^ cx)];
            acc = __builtin_amdgcn_mfma_f32_16x16x32_f16(aHH.h, bH.h, acc, 0, 0, 0);
        }
    }

    #pragma unroll
    for (int j = 0; j < 4; ++j) {
        const int ch = mt * 16 + g * 4 + j;
        if (ch < NCH) {
            float v = acc[j];
            if (ch < 18) v += offb[ch];
            else         v = 2.f / (1.f + expf(-(v + modb[ch - 18])));
            offm[((size_t)(b * NCH + ch)) * PB + row * 64 + pos] = v;
        }
    }
}

// ---------------------------------------------------------------- kernel 3
// r34: 16-wave WS deform conv, 6-deep ring, barrier per 3 chunks.
__global__ __launch_bounds__(1024, 1)
void deform_ws_kernel(const ushort* __restrict__ xhf,
                      const float* __restrict__ offm,
                      const ushort* __restrict__ wTb,
                      float* __restrict__ out)
{
    const int hw = blockIdx.x;
    const int blk = (hw & 7) * 32 + (hw >> 3);   // XCD swizzle (256 = 8*32)
    const int b = blk >> 6, row = blk & 63;
    const int p0 = row * 64;
    const int t = threadIdx.x;
    const int lane = t & 63;
    const int wv  = t >> 6;                      // 0..15
    const int l15 = lane & 15;
    const int g   = lane >> 4;

    __shared__ int4  s_off[576];       // [tap][pos 0..63]  (9216 B)
    __shared__ uint4 s_wgt[576];       // duplicated-fp16 weight pairs (9216 B)
    __shared__ uint  cols[6][4][1024]; // 6-deep ring (96 KB)

    for (int ti = t; ti < 576; ti += 1024) {
        const int k = ti >> 6, pos = ti & 63;
        const int p = p0 + pos;
        const float dy = offm[((size_t)(b * NCH + 2 * k)) * PB + p];
        const float dx = offm[((size_t)(b * NCH + 2 * k + 1)) * PB + p];
        const float m  = offm[((size_t)(b * NCH + 18 + k)) * PB + p];
        const int ky = k / 3, kx = k % 3;
        const float py = dy + (float)(ky + row - 1);
        const float px = dx + (float)(kx + pos - 1);
        const float y0f = floorf(py), x0f = floorf(px);
        const float fy = py - y0f, fx = px - x0f;
        const int y0 = (int)y0f, x0i = (int)x0f;
        const int y1 = y0 + 1, x1 = x0i + 1;
        const bool vy0 = (y0 >= 0) && (y0 < Hn);
        const bool vy1 = (y1 >= 0) && (y1 < Hn);
        const bool vx0 = (x0i >= 0) && (x0i < Wn);
        const bool vx1 = (x1 >= 0) && (x1 < Wn);
        const int y0c = min(max(y0, 0), Hn - 1);
        const int y1c = min(max(y1, 0), Hn - 1);
        const int x0c = min(max(x0i, 0), Wn - 1);
        const int x1c = min(max(x1, 0), Wn - 1);
        s_off[ti] = make_int4(y0c * Wn + x0c, y0c * Wn + x1c,
                              y1c * Wn + x0c, y1c * Wn + x1c);
        const float w0 = (vy0 && vx0) ? (1.f - fy) * (1.f - fx) * m : 0.f;
        const float w1 = (vy0 && vx1) ? (1.f - fy) * fx * m : 0.f;
        const float w2 = (vy1 && vx0) ? fy * (1.f - fx) * m : 0.f;
        const float w3 = (vy1 && vx1) ? fy * fx * m : 0.f;
        s_wgt[ti] = make_uint4(pkh(w0, w0), pkh(w1, w1),
                               pkh(w2, w2), pkh(w3, w3));
    }
    __syncthreads();   // tap tables visible to all waves

    const ushort* xb = xhf + (size_t)b * PB * 256;

    if (wv < 8) {
        // ===================== PRODUCER (waves 0-7) =====================
        const int chq  = t & 15;
        const int posT = t >> 4;          // 0..31
        const int sIdx = chq >> 2;
        const int grp  = (chq & 3) ^ (posT & 3) ^ ((posT >> 2) & 3);
        const int w4a  = posT * 4 + grp;  // pos posT+32 -> slot w4a + 128
        const ushort* xq = xb + 8 * chq;

        auto PISSUE = [&](int cch, uint4v (&gg)[2][4]) {
            const int tap = cch >> 1;
            const ushort* xcc = xq + (cch & 1) * 128;
            #pragma unroll
            for (int u = 0; u < 2; ++u) {
                const int4 o = s_off[tap * 64 + posT + u * 32];
                gg[u][0] = *reinterpret_cast<const uint4v*>(xcc + (size_t)o.x * 256);
                gg[u][1] = *reinterpret_cast<const uint4v*>(xcc + (size_t)o.y * 256);
                gg[u][2] = *reinterpret_cast<const uint4v*>(xcc + (size_t)o.z * 256);
                gg[u][3] = *reinterpret_cast<const uint4v*>(xcc + (size_t)o.w * 256);
            }
        };

        auto PCOMBINE = [&](int cch, const uint4v (&gg)[2][4], uint* cbuf) {
            const int tap = cch >> 1;
            uint4v* dst = reinterpret_cast<uint4v*>(cbuf + sIdx * 1024);
            #pragma unroll
            for (int u = 0; u < 2; ++u) {
                const uint4 wq = s_wgt[tap * 64 + posT + u * 32];
                uint pr[4];
                #pragma unroll
                for (int j = 0; j < 4; ++j) {
                    f16x2 v = u2h(gg[u][0][j]) * u2h(wq.x);
                    v += u2h(gg[u][1][j]) * u2h(wq.y);
                    v += u2h(gg[u][2][j]) * u2h(wq.z);
                    v += u2h(gg[u][3][j]) * u2h(wq.w);
                    pr[j] = h2u(v);
                }
                dst[w4a + u * 128] = (uint4v){pr[0], pr[1], pr[2], pr[3]};
            }
        };

        uint4v gA[2][4], gB[2][4];
        PISSUE(0, gA);
        #pragma unroll 1
        for (int mi = 0; mi < 3; ++mi) {
            const int c0 = 6 * mi;
            // ---- phase A: chunks c0..c0+2 -> slots 0,1,2 ----
            PISSUE(c0 + 1, gB);
            PCOMBINE(c0, gA, &cols[0][0][0]);       // waits oldest (gA)
            PISSUE(c0 + 2, gA);
            PCOMBINE(c0 + 1, gB, &cols[1][0][0]);
            PISSUE(c0 + 3, gB);
            PCOMBINE(c0 + 2, gA, &cols[2][0][0]);
            asm volatile("s_waitcnt lgkmcnt(0)" ::: "memory");
            __builtin_amdgcn_s_barrier();           // barrier #2mi
            asm volatile("" ::: "memory");
            // ---- phase B: chunks c0+3..c0+5 -> slots 3,4,5 ----
            PISSUE(c0 + 4, gA);
            PCOMBINE(c0 + 3, gB, &cols[3][0][0]);
            PISSUE(c0 + 5, gB);
            PCOMBINE(c0 + 4, gA, &cols[4][0][0]);
            if (mi < 2) PISSUE(c0 + 6, gA);
            PCOMBINE(c0 + 5, gB, &cols[5][0][0]);
            asm volatile("s_waitcnt lgkmcnt(0)" ::: "memory");
            __builtin_amdgcn_s_barrier();           // barrier #2mi+1
            asm volatile("" ::: "memory");
        }
    } else {
        // ===================== CONSUMER (waves 8-15) ====================
        const int cw = wv - 8;            // 0..7
        const int o0 = cw * 32;           // 32 outputs per consumer wave
        const uint4* wvp = reinterpret_cast<const uint4*>(wTb);

        int ri[4];
        #pragma unroll
        for (int nt = 0; nt < 4; ++nt) {
            const int p = nt * 16 + l15;
            ri[nt] = p * 4 + (g ^ (p & 3) ^ ((p >> 2) & 3));
        }

        f32x4 acc[2][4];
        #pragma unroll
        for (int i = 0; i < 2; ++i)
            #pragma unroll
            for (int nt = 0; nt < 4; ++nt)
                acc[i][nt] = (f32x4){0.f, 0.f, 0.f, 0.f};

        auto CLOADA = [&](int cch, uint4 (&ap)[4][2]) {
            #pragma unroll
            for (int s = 0; s < 4; ++s) {
                const int kb = (cch * 4 + s) * 4 + g;
                ap[s][0] = wvp[(size_t)kb * 256 + o0 + l15];
                ap[s][1] = wvp[(size_t)kb * 256 + o0 + 16 + l15];
            }
        };

        auto CMFMA = [&](const uint* cbuf, const uint4 (&ap)[4][2]) {
            __builtin_amdgcn_s_setprio(1);
            #pragma unroll
            for (int s = 0; s < 4; ++s) {
                FragU a0, a1, bf[4];
                a0.u = ap[s][0]; a1.u = ap[s][1];
                #pragma unroll
                for (int nt = 0; nt < 4; ++nt)
                    bf[nt].u = reinterpret_cast<const uint4*>(cbuf + s * 1024)[ri[nt]];
                #pragma unroll
                for (int nt = 0; nt < 4; ++nt) {
                    acc[0][nt] = __builtin_amdgcn_mfma_f32_16x16x32_f16(
                        a0.h, bf[nt].h, acc[0][nt], 0, 0, 0);
                    acc[1][nt] = __builtin_amdgcn_mfma_f32_16x16x32_f16(
                        a1.h, bf[nt].h, acc[1][nt], 0, 0, 0);
                }
            }
            __builtin_amdgcn_s_setprio(0);
        };

        uint4 aA[4][2], aB[4][2];
        CLOADA(0, aA);
        CLOADA(1, aB);
        #pragma unroll 1
        for (int mi = 0; mi < 3; ++mi) {
            const int c0 = 6 * mi;
            // ---- phase A: slots 0-2 = chunks c0..c0+2 ----
            __builtin_amdgcn_s_barrier();           // barrier #2mi
            asm volatile("" ::: "memory");
            CMFMA(&cols[0][0][0], aA);              // A(c0)
            CLOADA(c0 + 2, aA);
            CMFMA(&cols[1][0][0], aB);              // A(c0+1)
            CLOADA(c0 + 3, aB);
            CMFMA(&cols[2][0][0], aA);              // A(c0+2)
            CLOADA(c0 + 4, aA);
            // ---- phase B: slots 3-5 = chunks c0+3..c0+5 ----
            __builtin_amdgcn_s_barrier();           // barrier #2mi+1
            asm volatile("" ::: "memory");
            CMFMA(&cols[3][0][0], aB);              // A(c0+3)
            CLOADA(c0 + 5, aB);
            CMFMA(&cols[4][0][0], aA);              // A(c0+4)
            if (mi < 2) CLOADA(c0 + 6, aA);
            CMFMA(&cols[5][0][0], aB);              // A(c0+5)
            if (mi < 2) CLOADA(c0 + 7, aB);
        }

        float* ob = out + (size_t)b * On * PB;
        #pragma unroll
        for (int i = 0; i < 2; ++i)
            #pragma unroll
            for (int nt = 0; nt < 4; ++nt)
                #pragma unroll
                for (int j = 0; j < 4; ++j)
                    ob[((size_t)(o0 + i * 16 + g * 4 + j)) * PB
                       + p0 + nt * 16 + l15] = acc[i][nt][j];
    }
}

// ---------------------------------------------------------------- launch
extern "C" void kernel_launch(void* const* d_in, const int* in_sizes, int n_in,
                              void* d_out, int out_size, void* d_ws, size_t ws_size,
                              hipStream_t stream)
{
    const float* x    = (const float*)d_in[0];
    const float* offw = (const float*)d_in[1];
    const float* offb = (const float*)d_in[2];
    const float* modw = (const float*)d_in[3];
    const float* modb = (const float*)d_in[4];
    const float* wgt  = (const float*)d_in[5];
    float* out = (float*)d_out;

    char* ws = (char*)d_ws;
    float*  offm = (float*)ws;                   // 1,769,472 B
    ushort* wTb  = (ushort*)(ws + 1769472);      // 1,179,648 B
    ushort* owf  = (ushort*)(ws + 2949120);      // 147,456 B
    ushort* xhf  = (ushort*)(ws + 3244032);      // 8,388,608 B (fp16 NHWC)

    nhwcpack_kernel<<<dim3(512), dim3(256), 0, stream>>>(
        x, wgt, offw, modw, xhf, wTb, owf);
    offmask_tile_kernel<<<dim3(256), dim3(512), 0, stream>>>(
        xhf, offb, modb, owf, offm);
    deform_ws_kernel<<<dim3(256), dim3(1024), 0, stream>>>(
        xhf, offm, wTb, out);
}

// Round 18
// 52.730 us; speedup vs baseline: 1.0203x; 1.0203x over previous
//
#include <hip/hip_runtime.h>
#include <math.h>

// Modulated deformable conv v2: B=4, C=256, H=W=64, O=256, K=3, PAD=1
// r35 = r33 REVERT (final). r34's ring-6 regressed (53.8 vs 52.27): barrier
//      savings < prefetch-distance + LDS-footprint costs. Locking in the
//      best-measured configuration:
//      K1: r32 wide-op fp16 transpose + weight packs.
//      K2: r27 LDS-tile direct-read offset/mask conv (1 barrier).
//      K3: r33 16-wave producer/consumer WS deform conv, 4-deep cols ring,
//          barrier per 2 chunks (9 barriers), oldest-first vmcnt discipline.
//      Session: 77.0 -> 52.27 us (-32%).

constexpr int Bn = 4;
constexpr int Cn = 256;
constexpr int Hn = 64;
constexpr int Wn = 64;
constexpr int On = 256;
constexpr int PB = Hn * Wn;     // 4096
constexpr int NCH = 27;

typedef __attribute__((ext_vector_type(8))) _Float16 f16x8;  // 4 VGPRs
typedef __attribute__((ext_vector_type(2))) _Float16 f16x2;
typedef __attribute__((ext_vector_type(4))) float f32x4;
typedef __attribute__((ext_vector_type(4))) uint  uint4v;

union FragU { uint4 u; f16x8 h; };

__device__ inline ushort f2h(float f) {
    _Float16 h = (_Float16)f;
    return __builtin_bit_cast(ushort, h);
}
__device__ inline uint pkh(float a, float b) {
    return __builtin_bit_cast(uint, __builtin_amdgcn_cvt_pkrtz(a, b));
}
__device__ inline f16x2 u2h(uint u) { return __builtin_bit_cast(f16x2, u); }
__device__ inline uint h2u(f16x2 h) { return __builtin_bit_cast(uint, h); }

// ---------------------------------------------------------------- kernel 1
// r32: wide-op NCHW fp32 -> NHWC fp16 transpose + weight packs (verbatim).
__global__ __launch_bounds__(256)
void nhwcpack_kernel(const float* __restrict__ x,
                     const float* __restrict__ w,
                     const float* __restrict__ offw,
                     const float* __restrict__ modw,
                     ushort* __restrict__ xhf,
                     ushort* __restrict__ wTb,
                     ushort* __restrict__ owf)
{
    const int bid = blockIdx.x;
    const int b = bid >> 7, seg = bid & 127;
    const int t = threadIdx.x;
    __shared__ float tile2[256][36];   // channel-major; stride 36 -> 16B align

    {
        const int c0 = t >> 3;         // 0..31
        const int q  = t & 7;          // 0..7 -> positions 4q..4q+3
        const float* src = x + (size_t)b * Cn * PB + seg * 32 + 4 * q;
        #pragma unroll
        for (int i = 0; i < 8; ++i) {
            const int c = c0 + i * 32;
            const float4 v = *reinterpret_cast<const float4*>(src + (size_t)c * PB);
            *reinterpret_cast<float4*>(&tile2[c][4 * q]) = v;
        }
    }
    __syncthreads();

    {
        const int c2 = t & 127;        // output word column
        const int ph = t >> 7;         // 0..1
        uint* dH = reinterpret_cast<uint*>(xhf + ((size_t)b * PB + seg * 32) * 256);
        #pragma unroll
        for (int r = 0; r < 2; ++r) {
            const int ppb = (ph + 2 * r) * 8;     // 0,8,16,24
            const float4 a0 = *reinterpret_cast<const float4*>(&tile2[2 * c2][ppb]);
            const float4 a1 = *reinterpret_cast<const float4*>(&tile2[2 * c2][ppb + 4]);
            const float4 b0 = *reinterpret_cast<const float4*>(&tile2[2 * c2 + 1][ppb]);
            const float4 b1 = *reinterpret_cast<const float4*>(&tile2[2 * c2 + 1][ppb + 4]);
            uint wds[8];
            wds[0] = pkh(a0.x, b0.x); wds[1] = pkh(a0.y, b0.y);
            wds[2] = pkh(a0.z, b0.z); wds[3] = pkh(a0.w, b0.w);
            wds[4] = pkh(a1.x, b1.x); wds[5] = pkh(a1.y, b1.y);
            wds[6] = pkh(a1.z, b1.z); wds[7] = pkh(a1.w, b1.w);
            #pragma unroll
            for (int j = 0; j < 8; ++j)
                dH[(size_t)(ppb + j) * 128 + c2] = wds[j];
        }
    }

    #pragma unroll 1
    for (int u = 0; u < 5; ++u) {
        int unit = (u < 4) ? bid * 4 + u : (bid < 256 ? 2048 + bid : -1);
        if (unit < 0) break;
        const int tap = unit >> 8, c = unit & 255;
        const int o = t;
        wTb[((size_t)(unit >> 3) * 256 + o) * 8 + (c & 7)] =
            f2h(w[((size_t)o * Cn + c) * 9 + tap]);
        if (o < 32) {
            float v = 0.f;
            if (o < 18)      v = offw[((size_t)o * Cn + c) * 9 + tap];
            else if (o < 27) v = modw[((size_t)(o - 18) * Cn + c) * 9 + tap];
            owf[((size_t)(unit >> 3) * 32 + o) * 8 + (c & 7)] = f2h(v);
        }
    }
}

// ---------------------------------------------------------------- kernel 2
// r27: offset/mask conv via LDS x-tile direct read (verbatim).
__global__ __launch_bounds__(512, 1)
void offmask_tile_kernel(const ushort* __restrict__ xhf,
                         const float* __restrict__ offb,
                         const float* __restrict__ modb,
                         const ushort* __restrict__ owf,
                         float* __restrict__ offm)
{
    const int hw = blockIdx.x;
    const int blk = (hw & 7) * 32 + (hw >> 3);
    const int b = blk >> 6, row = blk & 63;
    const int t = threadIdx.x;
    const int lane = t & 63;
    const int wv  = t >> 6;
    const int l15 = lane & 15;
    const int g   = lane >> 4;
    const int mt  = wv >> 2;
    const int nt  = wv & 3;

    __shared__ ushort xt[3 * 66 * 256];          // 101,376 B
    uint4* lds4 = reinterpret_cast<uint4*>(xt);  // 16B octets

    {
        const int c  = t >> 3;           // 0..63
        const int og = (t & 7) * 4;      // starting octet 0,4,..,28
        #pragma unroll 1
        for (int r = 0; r < 3; ++r) {
            const int ysrc = row - 1 + r;
            const int ci = c + 1;
            const int base = (r * 66 + ci) * 32;
            if (ysrc >= 0 && ysrc < Hn) {
                const uint4* src = reinterpret_cast<const uint4*>(
                    xhf + ((size_t)(b * PB + ysrc * 64 + c)) * 256);
                #pragma unroll
                for (int j = 0; j < 4; ++j) {
                    const int o = og + j;
                    lds4[base + (o ^ (ci & 7))] = src[o];
                }
            } else {
                const uint4 z = make_uint4(0u, 0u, 0u, 0u);
                #pragma unroll
                for (int j = 0; j < 4; ++j) {
                    const int o = og + j;
                    lds4[base + (o ^ (ci & 7))] = z;
                }
            }
        }
        if (t < 192) {
            const int r = t >> 6, idx = t & 63;
            const int ci = (idx >= 32) ? 65 : 0;
            const int o = idx & 31;
            lds4[(r * 66 + ci) * 32 + (o ^ (ci & 7))] =
                make_uint4(0u, 0u, 0u, 0u);
        }
    }
    __syncthreads();   // the ONLY barrier

    const uint4* owfV = reinterpret_cast<const uint4*>(owf);
    f32x4 acc = (f32x4){0.f, 0.f, 0.f, 0.f};
    const int pos = nt * 16 + l15;

    #pragma unroll 1
    for (int tap = 0; tap < 9; ++tap) {
        const int ty = tap / 3, tx = tap % 3;
        const int ci = pos + tx;
        const int cbase = (ty * 66 + ci) * 32;
        const int cx = ci & 7;

        uint4 aH[8];
        #pragma unroll
        for (int s = 0; s < 8; ++s) {
            const size_t kb = (size_t)((tap * 8 + s) * 4 + g) * 32 + mt * 16 + l15;
            aH[s] = owfV[kb];
        }

        #pragma unroll
        for (int s = 0; s < 8; ++s) {
            FragU aHH, bH;
            aHH.u = aH[s];
            bH.u = lds4[cbase + ((4 * s + g) ^ cx)];
            acc = __builtin_amdgcn_mfma_f32_16x16x32_f16(aHH.h, bH.h, acc, 0, 0, 0);
        }
    }

    #pragma unroll
    for (int j = 0; j < 4; ++j) {
        const int ch = mt * 16 + g * 4 + j;
        if (ch < NCH) {
            float v = acc[j];
            if (ch < 18) v += offb[ch];
            else         v = 2.f / (1.f + expf(-(v + modb[ch - 18])));
            offm[((size_t)(b * NCH + ch)) * PB + row * 64 + pos] = v;
        }
    }
}

// ---------------------------------------------------------------- kernel 3
// r33: 16-wave WS deform conv, 4-deep ring, barrier per 2 chunks (verbatim).
__global__ __launch_bounds__(1024, 1)
void deform_ws_kernel(const ushort* __restrict__ xhf,
                      const float* __restrict__ offm,
                      const ushort* __restrict__ wTb,
                      float* __restrict__ out)
{
    const int hw = blockIdx.x;
    const int blk = (hw & 7) * 32 + (hw >> 3);   // XCD swizzle (256 = 8*32)
    const int b = blk >> 6, row = blk & 63;
    const int p0 = row * 64;
    const int t = threadIdx.x;
    const int lane = t & 63;
    const int wv  = t >> 6;                      // 0..15
    const int l15 = lane & 15;
    const int g   = lane >> 4;

    __shared__ int4  s_off[576];       // [tap][pos 0..63]
    __shared__ uint4 s_wgt[576];       // duplicated-fp16 weight pairs
    __shared__ uint  cols[4][4][1024]; // 4-deep ring (64 KB)

    for (int ti = t; ti < 576; ti += 1024) {
        const int k = ti >> 6, pos = ti & 63;
        const int p = p0 + pos;
        const float dy = offm[((size_t)(b * NCH + 2 * k)) * PB + p];
        const float dx = offm[((size_t)(b * NCH + 2 * k + 1)) * PB + p];
        const float m  = offm[((size_t)(b * NCH + 18 + k)) * PB + p];
        const int ky = k / 3, kx = k % 3;
        const float py = dy + (float)(ky + row - 1);
        const float px = dx + (float)(kx + pos - 1);
        const float y0f = floorf(py), x0f = floorf(px);
        const float fy = py - y0f, fx = px - x0f;
        const int y0 = (int)y0f, x0i = (int)x0f;
        const int y1 = y0 + 1, x1 = x0i + 1;
        const bool vy0 = (y0 >= 0) && (y0 < Hn);
        const bool vy1 = (y1 >= 0) && (y1 < Hn);
        const bool vx0 = (x0i >= 0) && (x0i < Wn);
        const bool vx1 = (x1 >= 0) && (x1 < Wn);
        const int y0c = min(max(y0, 0), Hn - 1);
        const int y1c = min(max(y1, 0), Hn - 1);
        const int x0c = min(max(x0i, 0), Wn - 1);
        const int x1c = min(max(x1, 0), Wn - 1);
        s_off[ti] = make_int4(y0c * Wn + x0c, y0c * Wn + x1c,
                              y1c * Wn + x0c, y1c * Wn + x1c);
        const float w0 = (vy0 && vx0) ? (1.f - fy) * (1.f - fx) * m : 0.f;
        const float w1 = (vy0 && vx1) ? (1.f - fy) * fx * m : 0.f;
        const float w2 = (vy1 && vx0) ? fy * (1.f - fx) * m : 0.f;
        const float w3 = (vy1 && vx1) ? fy * fx * m : 0.f;
        s_wgt[ti] = make_uint4(pkh(w0, w0), pkh(w1, w1),
                               pkh(w2, w2), pkh(w3, w3));
    }
    __syncthreads();   // tap tables visible to all waves

    const ushort* xb = xhf + (size_t)b * PB * 256;

    if (wv < 8) {
        // ===================== PRODUCER (waves 0-7) =====================
        const int chq  = t & 15;
        const int posT = t >> 4;          // 0..31
        const int sIdx = chq >> 2;
        const int grp  = (chq & 3) ^ (posT & 3) ^ ((posT >> 2) & 3);
        const int w4a  = posT * 4 + grp;  // pos posT+32 -> slot w4a + 128
        const ushort* xq = xb + 8 * chq;

        auto PISSUE = [&](int cch, uint4v (&gg)[2][4]) {
            const int tap = cch >> 1;
            const ushort* xcc = xq + (cch & 1) * 128;
            #pragma unroll
            for (int u = 0; u < 2; ++u) {
                const int4 o = s_off[tap * 64 + posT + u * 32];
                gg[u][0] = *reinterpret_cast<const uint4v*>(xcc + (size_t)o.x * 256);
                gg[u][1] = *reinterpret_cast<const uint4v*>(xcc + (size_t)o.y * 256);
                gg[u][2] = *reinterpret_cast<const uint4v*>(xcc + (size_t)o.z * 256);
                gg[u][3] = *reinterpret_cast<const uint4v*>(xcc + (size_t)o.w * 256);
            }
        };

        auto PCOMBINE = [&](int cch, const uint4v (&gg)[2][4], uint* cbuf) {
            const int tap = cch >> 1;
            uint4v* dst = reinterpret_cast<uint4v*>(cbuf + sIdx * 1024);
            #pragma unroll
            for (int u = 0; u < 2; ++u) {
                const uint4 wq = s_wgt[tap * 64 + posT + u * 32];
                uint pr[4];
                #pragma unroll
                for (int j = 0; j < 4; ++j) {
                    f16x2 v = u2h(gg[u][0][j]) * u2h(wq.x);
                    v += u2h(gg[u][1][j]) * u2h(wq.y);
                    v += u2h(gg[u][2][j]) * u2h(wq.z);
                    v += u2h(gg[u][3][j]) * u2h(wq.w);
                    pr[j] = h2u(v);
                }
                dst[w4a + u * 128] = (uint4v){pr[0], pr[1], pr[2], pr[3]};
            }
        };

        uint4v gA[2][4], gB[2][4];
        PISSUE(0, gA);
        #pragma unroll 1
        for (int jj = 0; jj < 9; ++jj) {
            const int sb = (jj & 1) * 2;            // slots sb, sb+1
            PISSUE(2 * jj + 1, gB);
            PCOMBINE(2 * jj, gA, &cols[sb][0][0]);  // waits oldest gathers
            if (jj < 8) PISSUE(2 * jj + 2, gA);     // after gA consumed
            PCOMBINE(2 * jj + 1, gB, &cols[sb + 1][0][0]);
            asm volatile("s_waitcnt lgkmcnt(0)" ::: "memory");
            __builtin_amdgcn_s_barrier();           // ONE barrier / 2 chunks
            asm volatile("" ::: "memory");
        }
    } else {
        // ===================== CONSUMER (waves 8-15) ====================
        const int cw = wv - 8;            // 0..7
        const int o0 = cw * 32;           // 32 outputs per consumer wave
        const uint4* wvp = reinterpret_cast<const uint4*>(wTb);

        int ri[4];
        #pragma unroll
        for (int nt = 0; nt < 4; ++nt) {
            const int p = nt * 16 + l15;
            ri[nt] = p * 4 + (g ^ (p & 3) ^ ((p >> 2) & 3));
        }

        f32x4 acc[2][4];
        #pragma unroll
        for (int i = 0; i < 2; ++i)
            #pragma unroll
            for (int nt = 0; nt < 4; ++nt)
                acc[i][nt] = (f32x4){0.f, 0.f, 0.f, 0.f};

        auto CLOADA = [&](int cch, uint4 (&ap)[4][2]) {
            #pragma unroll
            for (int s = 0; s < 4; ++s) {
                const int kb = (cch * 4 + s) * 4 + g;
                ap[s][0] = wvp[(size_t)kb * 256 + o0 + l15];
                ap[s][1] = wvp[(size_t)kb * 256 + o0 + 16 + l15];
            }
        };

        auto CMFMA = [&](const uint* cbuf, const uint4 (&ap)[4][2]) {
            __builtin_amdgcn_s_setprio(1);
            #pragma unroll
            for (int s = 0; s < 4; ++s) {
                FragU a0, a1, bf[4];
                a0.u = ap[s][0]; a1.u = ap[s][1];
                #pragma unroll
                for (int nt = 0; nt < 4; ++nt)
                    bf[nt].u = reinterpret_cast<const uint4*>(cbuf + s * 1024)[ri[nt]];
                #pragma unroll
                for (int nt = 0; nt < 4; ++nt) {
                    acc[0][nt] = __builtin_amdgcn_mfma_f32_16x16x32_f16(
                        a0.h, bf[nt].h, acc[0][nt], 0, 0, 0);
                    acc[1][nt] = __builtin_amdgcn_mfma_f32_16x16x32_f16(
                        a1.h, bf[nt].h, acc[1][nt], 0, 0, 0);
                }
            }
            __builtin_amdgcn_s_setprio(0);
        };

        uint4 aA[4][2], aB[4][2];
        CLOADA(0, aA);
        CLOADA(1, aB);
        #pragma unroll 1
        for (int jj = 0; jj < 9; ++jj) {
            const int sb = (jj & 1) * 2;
            __builtin_amdgcn_s_barrier();           // chunks 2jj,2jj+1 ready
            asm volatile("" ::: "memory");
            CMFMA(&cols[sb][0][0], aA);
            if (jj < 8) CLOADA(2 * jj + 2, aA);     // lands during next phase
            CMFMA(&cols[sb + 1][0][0], aB);
            if (jj < 8) CLOADA(2 * jj + 3, aB);
        }

        float* ob = out + (size_t)b * On * PB;
        #pragma unroll
        for (int i = 0; i < 2; ++i)
            #pragma unroll
            for (int nt = 0; nt < 4; ++nt)
                #pragma unroll
                for (int j = 0; j < 4; ++j)
                    ob[((size_t)(o0 + i * 16 + g * 4 + j)) * PB
                       + p0 + nt * 16 + l15] = acc[i][nt][j];
    }
}

// ---------------------------------------------------------------- launch
extern "C" void kernel_launch(void* const* d_in, const int* in_sizes, int n_in,
                              void* d_out, int out_size, void* d_ws, size_t ws_size,
                              hipStream_t stream)
{
    const float* x    = (const float*)d_in[0];
    const float* offw = (const float*)d_in[1];
    const float* offb = (const float*)d_in[2];
    const float* modw = (const float*)d_in[3];
    const float* modb = (const float*)d_in[4];
    const float* wgt  = (const float*)d_in[5];
    float* out = (float*)d_out;

    char* ws = (char*)d_ws;
    float*  offm = (float*)ws;                   // 1,769,472 B
    ushort* wTb  = (ushort*)(ws + 1769472);      // 1,179,648 B
    ushort* owf  = (ushort*)(ws + 2949120);      // 147,456 B
    ushort* xhf  = (ushort*)(ws + 3244032);      // 8,388,608 B (fp16 NHWC)

    nhwcpack_kernel<<<dim3(512), dim3(256), 0, stream>>>(
        x, wgt, offw, modw, xhf, wTb, owf);
    offmask_tile_kernel<<<dim3(256), dim3(512), 0, stream>>>(
        xhf, offb, modb, owf, offm);
    deform_ws_kernel<<<dim3(256), dim3(1024), 0, stream>>>(
        xhf, offm, wTb, out);
}